// Round 12
// baseline (165.581 us; speedup 1.0000x reference)
//
#include <hip/hip_runtime.h>
#include <math.h>

#define NN 325
#define BT 96
#define NROWS (BT * NN)   // 31200 = 975 * 32 exactly
// fold softmax scale and log2(e) into q: exp(s/sqrt8) == exp2(s * SCL)
#define SCL (0.35355339059327373f * 1.4426950408889634f)

typedef _Float16 half_t;
typedef half_t half4_t __attribute__((ext_vector_type(4)));
typedef half_t half2_t __attribute__((ext_vector_type(2)));
typedef float float4_t __attribute__((ext_vector_type(4)));

__device__ __forceinline__ float gelu_f(float x) {
    return 0.5f * x * (1.0f + erff(x * 0.70710678118654752f));
}

// ---------------------------------------------------------------------------
// Kernel 0 (prep): pack adj bitmasks + convert all 5 weight matrices to f16.
// ---------------------------------------------------------------------------
__global__ void prep_kernel(const int* __restrict__ adj,
                            const float* __restrict__ W7,
                            const float* __restrict__ W8,
                            const float* __restrict__ W9,
                            const float* __restrict__ W10,
                            const float* __restrict__ W11,
                            unsigned int* __restrict__ packedT,
                            half_t* __restrict__ w789,
                            half_t* __restrict__ wab)
{
    int idx = blockIdx.x * 256 + threadIdx.x;
    if (idx < 11 * NN) {
        int w = idx / NN, n = idx - w * NN;
        unsigned int bits = 0u;
        #pragma unroll 8
        for (int j = 0; j < 32; ++j) {
            int m = w * 32 + j;
            if (m < NN && adj[n * NN + m] > 0) bits |= (1u << j);
        }
        packedT[w * NN + n] = bits;
    } else if (idx < 3575 + 24576) {
        int i = idx - 3575;
        int p = i >> 13, r = i & 8191;
        const float* Wp = (p == 0) ? W7 : (p == 1) ? W8 : W9;
        w789[i] = (half_t)Wp[r];
    } else if (idx < 3575 + 24576 + 8192) {
        int i = idx - 28151;
        int p = i >> 12, r = i & 4095;
        wab[i] = (half_t)(p ? W11[r] : W10[r]);
    }
}

// ---------------------------------------------------------------------------
// Kernel 1: q/k/v = gelu(concat(X,STE) @ W.T + b) via f16 MFMA.
// SINGLE-BARRIER version: stage x (32 rows) + ALL 192 weight rows at once
// (60.9 KB LDS), then each wave does 6 col-tiles x 8 k-steps = 48 MFMA
// with no further barriers.  [R12 fix: weight staging covers the FULL
// 128-half row — 16 chunks of 8 halfs, not 8 chunks 16 apart.]
// ---------------------------------------------------------------------------
#define XS 136   // half stride per 128-k row

__global__ __launch_bounds__(256) void qkv_kernel(
    const float* __restrict__ X, const float* __restrict__ STE,
    const half_t* __restrict__ w789,
    const float* __restrict__ b7, const float* __restrict__ b8,
    const float* __restrict__ b9,
    half_t* __restrict__ q, half_t* __restrict__ k, half_t* __restrict__ v)
{
    __shared__ __attribute__((aligned(16))) half_t x16[32 * XS];
    __shared__ __attribute__((aligned(16))) half_t w16[192 * XS];
    const int tid  = threadIdx.x;
    const int row0 = blockIdx.x * 32;

    // stage x = concat(X, STE) -> f16 (exact grid: no row guards)
    #pragma unroll
    for (int idx = tid; idx < 1024; idx += 256) {
        int r = idx >> 5, c4 = idx & 31;
        int R = row0 + r;
        float4 f = (c4 < 16) ? *(const float4*)(X + (long)R * 64 + c4 * 4)
                             : *(const float4*)(STE + (long)R * 64 + (c4 - 16) * 4);
        half4_t hv;
        hv[0] = (half_t)f.x; hv[1] = (half_t)f.y;
        hv[2] = (half_t)f.z; hv[3] = (half_t)f.w;
        *(half4_t*)&x16[r * XS + c4 * 4] = hv;
    }
    // stage all 192 weight rows (f16, native [c][k] layout)
    // 192 rows x 16 uint4-chunks (8 halfs each) = 3072 transfers
    #pragma unroll
    for (int idx = tid; idx < 3072; idx += 256) {
        int c = idx >> 4, g = idx & 15;
        *(uint4*)&w16[c * XS + g * 8] = *(const uint4*)&w789[c * 128 + g * 8];
    }
    __syncthreads();

    const int lane = tid & 63, wv = tid >> 6;
    const int l15 = lane & 15, quad = lane >> 4;
    const int rbase = (wv & 1) * 16;        // row tile
    const int chalf = wv >> 1;              // 96-col half

    // preload the 8 A fragments (reused across 6 col-tiles)
    half4_t af[8];
    #pragma unroll
    for (int kk = 0; kk < 8; ++kk)
        af[kk] = *(const half4_t*)&x16[(rbase + l15) * XS + kk * 16 + quad * 4];

    #pragma unroll
    for (int ct = 0; ct < 6; ++ct) {
        const int gcol = chalf * 96 + ct * 16;   // 0..176
        const int mat  = gcol >> 6;              // 0,1,2
        const int lc   = gcol & 63;
        const float* bb = (mat == 0) ? b7 : (mat == 1) ? b8 : b9;
        half_t* outp    = (mat == 0) ? q  : (mat == 1) ? k  : v;
        const float osc = (mat == 0) ? SCL : 1.0f;

        float bias = bb[lc + l15];
        float4_t acc = (float4_t){bias, bias, bias, bias};
        #pragma unroll
        for (int kk = 0; kk < 8; ++kk) {
            half4_t bf = *(const half4_t*)
                &w16[(gcol + l15) * XS + kk * 16 + quad * 4];
            acc = __builtin_amdgcn_mfma_f32_16x16x16f16(af[kk], bf, acc, 0, 0, 0);
        }
        #pragma unroll
        for (int rr = 0; rr < 4; ++rr) {
            int R = row0 + rbase + quad * 4 + rr;
            outp[(long)R * 64 + lc + l15] = (half_t)(gelu_f(acc[rr]) * osc);
        }
    }
}

// ---------------------------------------------------------------------------
// Kernel 2: MFMA flash attention v3 (R9 config: grid (8,96), 21 tiles over
// 4 waves). mt loops unroll-bounded to 7 (I-cache/ILP test vs full unroll).
// ---------------------------------------------------------------------------
__global__ __launch_bounds__(256) void attn_kernel(
    const half_t* __restrict__ q16g, const half_t* __restrict__ k16g,
    const half_t* __restrict__ v16g, const unsigned int* __restrict__ packedT,
    half_t* __restrict__ ao)
{
    __shared__ __attribute__((aligned(16))) half_t K16[336 * 20]; // [m][d0..15,pad]
    __shared__ __attribute__((aligned(16))) half_t VT16[16 * 344];// [c][m]
    const int tid = threadIdx.x;
    const int h = blockIdx.x, bt = blockIdx.y;
    const long base = (long)(bt * NN) * 64 + h * 8;

    const half4_t z4 = {(half_t)0.f, (half_t)0.f, (half_t)0.f, (half_t)0.f};

    // zero VT16, then ones row c=8 (sum-via-MFMA trick)
    for (int idx = tid; idx < 16 * 344 / 2; idx += 256)
        ((half2_t*)VT16)[idx] = (half2_t)(half_t)0.f;
    __syncthreads();
    for (int i = tid; i < 344; i += 256)
        VT16[8 * 344 + i] = (half_t)1.0f;

    // stage K rows (stride 20, d 8..15 zero)
    for (int r = tid; r < 336; r += 256) {
        half4_t ka = z4, kb = z4;
        if (r < NN) {
            ka = *(const half4_t*)(k16g + base + r * 64);
            kb = *(const half4_t*)(k16g + base + r * 64 + 4);
        }
        *(half4_t*)&K16[r * 20]      = ka;
        *(half4_t*)&K16[r * 20 + 4]  = kb;
        *(half4_t*)&K16[r * 20 + 8]  = z4;
        *(half4_t*)&K16[r * 20 + 12] = z4;
    }

    // stage V transposed via m-pair half2 writes (rows c = 0..7)
    for (int mp = tid; mp < 168; mp += 256) {
        int m0 = 2 * mp, m1 = 2 * mp + 1;
        half4_t v0a = z4, v0b = z4, v1a = z4, v1b = z4;
        if (m0 < NN) {
            v0a = *(const half4_t*)(v16g + base + m0 * 64);
            v0b = *(const half4_t*)(v16g + base + m0 * 64 + 4);
        }
        if (m1 < NN) {
            v1a = *(const half4_t*)(v16g + base + m1 * 64);
            v1b = *(const half4_t*)(v16g + base + m1 * 64 + 4);
        }
        #pragma unroll
        for (int c = 0; c < 4; ++c) {
            half2_t p0; p0[0] = v0a[c]; p0[1] = v1a[c];
            half2_t p1; p1[0] = v0b[c]; p1[1] = v1b[c];
            *(half2_t*)&VT16[c * 344 + 2 * mp]       = p0;
            *(half2_t*)&VT16[(c + 4) * 344 + 2 * mp] = p1;
        }
    }
    __syncthreads();

    const int lane = tid & 63;
    const int wv   = tid >> 6;
    const int l15  = lane & 15;
    const int quad = lane >> 4;
    const int qsh  = quad * 4;

    for (int t = wv; t < 21; t += 4) {
        const int n  = t * 16 + l15;
        const int nq = (n < NN) ? n : (NN - 1);   // clamp for global reads

        half4_t qf = z4;
        if (quad < 2)
            qf = *(const half4_t*)(q16g + base + (long)nq * 64 + qsh);

        // pass A: unmasked row max (>= all masked s; padded rows give s=0)
        float rm = 0.0f;
        #pragma unroll 7
        for (int mt = 0; mt < 21; ++mt) {
            half4_t kf = *(const half4_t*)&K16[(mt * 16 + l15) * 20 + qsh];
            float4_t s = __builtin_amdgcn_mfma_f32_16x16x16f16(
                kf, qf, (float4_t){0.f, 0.f, 0.f, 0.f}, 0, 0, 0);
            rm = fmaxf(rm, fmaxf(fmaxf(s[0], s[1]), fmaxf(s[2], s[3])));
        }
        rm = fmaxf(rm, __shfl_xor(rm, 16, 64));
        rm = fmaxf(rm, __shfl_xor(rm, 32, 64));

        // mask words for this row
        unsigned int mb[11];
        #pragma unroll
        for (int w = 0; w < 11; ++w) mb[w] = packedT[w * NN + nq];

        // pass B: s' = K.Q^T - rm (C-operand), p = exp2(s'), sum via ones-row
        const float4_t cinit = {-rm, -rm, -rm, -rm};
        float4_t acc = {0.f, 0.f, 0.f, 0.f};
        #pragma unroll 7
        for (int mt = 0; mt < 21; ++mt) {
            half4_t kf = *(const half4_t*)&K16[(mt * 16 + l15) * 20 + qsh];
            float4_t s = __builtin_amdgcn_mfma_f32_16x16x16f16(
                kf, qf, cinit, 0, 0, 0);
            unsigned int sh = mb[mt >> 1] >> (((mt & 1) << 4) + qsh);
            float p0 = (sh & 1u) ? __builtin_amdgcn_exp2f(s[0]) : 0.f;
            float p1 = (sh & 2u) ? __builtin_amdgcn_exp2f(s[1]) : 0.f;
            float p2 = (sh & 4u) ? __builtin_amdgcn_exp2f(s[2]) : 0.f;
            float p3 = (sh & 8u) ? __builtin_amdgcn_exp2f(s[3]) : 0.f;
            half4_t pf;
            pf[0] = (half_t)p0; pf[1] = (half_t)p1;
            pf[2] = (half_t)p2; pf[3] = (half_t)p3;
            half4_t vf = *(const half4_t*)&VT16[l15 * 344 + mt * 16 + qsh];
            acc = __builtin_amdgcn_mfma_f32_16x16x16f16(vf, pf, acc, 0, 0, 0);
        }

        // sum for row n lives in lane (quad=2).acc[0]  (ones row c=8)
        float sum = __shfl(acc[0], 32 + l15, 64);

        if (quad < 2 && n < NN) {
            float inv = 1.0f / sum;
            half4_t o;
            o[0] = (half_t)(acc[0] * inv); o[1] = (half_t)(acc[1] * inv);
            o[2] = (half_t)(acc[2] * inv); o[3] = (half_t)(acc[3] * inv);
            *(half4_t*)(ao + base + (long)n * 64 + qsh) = o;
        }
    }
}

// ---------------------------------------------------------------------------
// Kernel 3: out = gelu(ao @ W10.T + b10) @ W11.T + b11 via f16 MFMA.
// R9 version (32 rows/block, 256 thr, 975 blocks) — unchanged.
// ---------------------------------------------------------------------------
#define PS 72   // half stride per 64-k row

__global__ __launch_bounds__(256) void proj_kernel(
    const half_t* __restrict__ ao, const half_t* __restrict__ wab,
    const float* __restrict__ b10, const float* __restrict__ b11,
    float* __restrict__ out)
{
    __shared__ __attribute__((aligned(16))) half_t a16[32 * PS];
    __shared__ __attribute__((aligned(16))) half_t h16[32 * PS];
    __shared__ __attribute__((aligned(16))) half_t wA[64 * PS];
    __shared__ __attribute__((aligned(16))) half_t wB[64 * PS];
    const int tid  = threadIdx.x;
    const int row0 = blockIdx.x * 32;

    #pragma unroll
    for (int idx = tid; idx < 256; idx += 256) {
        int r = idx >> 3, c8 = idx & 7;
        *(uint4*)&a16[r * PS + c8 * 8] =
            *(const uint4*)(ao + (long)(row0 + r) * 64 + c8 * 8);
    }
    #pragma unroll
    for (int idx = tid; idx < 512; idx += 256) {
        int r = idx >> 3, c8 = idx & 7;
        *(uint4*)&wA[r * PS + c8 * 8] = *(const uint4*)&wab[r * 64 + c8 * 8];
        *(uint4*)&wB[r * PS + c8 * 8] = *(const uint4*)&wab[4096 + r * 64 + c8 * 8];
    }
    __syncthreads();

    const int lane = tid & 63, wv = tid >> 6;
    const int l15 = lane & 15, quad = lane >> 4;
    const int rbase = (wv & 1) * 16, ch = wv >> 1;

    // stage 1: h = gelu(a @ W10.T + b10)
    float4_t acc[2];
    #pragma unroll
    for (int cc = 0; cc < 2; ++cc) {
        float bias = b10[(ch * 2 + cc) * 16 + l15];
        acc[cc] = (float4_t){bias, bias, bias, bias};
    }
    #pragma unroll
    for (int kk = 0; kk < 4; ++kk) {
        half4_t a = *(const half4_t*)&a16[(rbase + l15) * PS + kk * 16 + quad * 4];
        #pragma unroll
        for (int cc = 0; cc < 2; ++cc) {
            half4_t bf = *(const half4_t*)
                &wA[((ch * 2 + cc) * 16 + l15) * PS + kk * 16 + quad * 4];
            acc[cc] = __builtin_amdgcn_mfma_f32_16x16x16f16(a, bf, acc[cc], 0, 0, 0);
        }
    }
    #pragma unroll
    for (int cc = 0; cc < 2; ++cc) {
        #pragma unroll
        for (int rr = 0; rr < 4; ++rr)
            h16[(rbase + quad * 4 + rr) * PS + (ch * 2 + cc) * 16 + l15] =
                (half_t)gelu_f(acc[cc][rr]);
    }
    __syncthreads();

    // stage 2: out = h @ W11.T + b11
    #pragma unroll
    for (int cc = 0; cc < 2; ++cc) {
        float bias = b11[(ch * 2 + cc) * 16 + l15];
        acc[cc] = (float4_t){bias, bias, bias, bias};
    }
    #pragma unroll
    for (int kk = 0; kk < 4; ++kk) {
        half4_t a = *(const half4_t*)&h16[(rbase + l15) * PS + kk * 16 + quad * 4];
        #pragma unroll
        for (int cc = 0; cc < 2; ++cc) {
            half4_t bf = *(const half4_t*)
                &wB[((ch * 2 + cc) * 16 + l15) * PS + kk * 16 + quad * 4];
            acc[cc] = __builtin_amdgcn_mfma_f32_16x16x16f16(a, bf, acc[cc], 0, 0, 0);
        }
    }
    #pragma unroll
    for (int cc = 0; cc < 2; ++cc) {
        #pragma unroll
        for (int rr = 0; rr < 4; ++rr) {
            int R = row0 + rbase + quad * 4 + rr;
            out[R * 64 + (ch * 2 + cc) * 16 + l15] = acc[cc][rr];
        }
    }
}

extern "C" void kernel_launch(void* const* d_in, const int* in_sizes, int n_in,
                              void* d_out, int out_size, void* d_ws, size_t ws_size,
                              hipStream_t stream) {
    const float* X   = (const float*)d_in[0];
    const float* STE = (const float*)d_in[1];
    const int*   adj = (const int*)d_in[2];
    const float* W7  = (const float*)d_in[3];
    const float* b7  = (const float*)d_in[4];
    const float* W8  = (const float*)d_in[5];
    const float* b8  = (const float*)d_in[6];
    const float* W9  = (const float*)d_in[7];
    const float* b9  = (const float*)d_in[8];
    const float* W10 = (const float*)d_in[9];
    const float* b10 = (const float*)d_in[10];
    const float* W11 = (const float*)d_in[11];
    const float* b11 = (const float*)d_in[12];

    char* wsb = (char*)d_ws;
    const long S = (long)NROWS * 64;           // 1,996,800 elements
    half_t* qb = (half_t*)wsb;
    half_t* kb = qb + S;
    half_t* vb = qb + 2 * S;
    half_t* ab = qb + 3 * S;
    unsigned int* pk = (unsigned int*)(wsb + 4 * S * sizeof(half_t));
    half_t* w789 = (half_t*)(wsb + 4 * S * sizeof(half_t) + 16384);
    half_t* wab  = w789 + 24576;

    prep_kernel<<<142, 256, 0, stream>>>(adj, W7, W8, W9, W10, W11,
                                         pk, w789, wab);
    qkv_kernel<<<dim3(975), 256, 0, stream>>>(
        X, STE, w789, b7, b8, b9, qb, kb, vb);
    attn_kernel<<<dim3(8, BT), 256, 0, stream>>>(qb, kb, vb, pk, ab);
    proj_kernel<<<dim3(975), 256, 0, stream>>>(
        ab, wab, b10, b11, (float*)d_out);
}

// Round 13
// 155.251 us; speedup vs baseline: 1.0665x; 1.0665x over previous
//
#include <hip/hip_runtime.h>
#include <math.h>

#define NN 325
#define BT 96
#define NROWS (BT * NN)   // 31200
// fold softmax scale and log2(e) into q: exp(s/sqrt8) == exp2(s * SCL)
#define SCL (0.35355339059327373f * 1.4426950408889634f)

typedef _Float16 half_t;
typedef half_t half4_t __attribute__((ext_vector_type(4)));
typedef half_t half2_t __attribute__((ext_vector_type(2)));
typedef float float4_t __attribute__((ext_vector_type(4)));

__device__ __forceinline__ float gelu_f(float x) {
    return 0.5f * x * (1.0f + erff(x * 0.70710678118654752f));
}

// ---------------------------------------------------------------------------
// Kernel 0 (prep): pack adj bitmasks + convert all 5 weight matrices to f16.
// ---------------------------------------------------------------------------
__global__ void prep_kernel(const int* __restrict__ adj,
                            const float* __restrict__ W7,
                            const float* __restrict__ W8,
                            const float* __restrict__ W9,
                            const float* __restrict__ W10,
                            const float* __restrict__ W11,
                            unsigned int* __restrict__ packedT,
                            half_t* __restrict__ w789,
                            half_t* __restrict__ wab)
{
    int idx = blockIdx.x * 256 + threadIdx.x;
    if (idx < 11 * NN) {
        int w = idx / NN, n = idx - w * NN;
        unsigned int bits = 0u;
        #pragma unroll 8
        for (int j = 0; j < 32; ++j) {
            int m = w * 32 + j;
            if (m < NN && adj[n * NN + m] > 0) bits |= (1u << j);
        }
        packedT[w * NN + n] = bits;
    } else if (idx < 3575 + 24576) {
        int i = idx - 3575;
        int p = i >> 13, r = i & 8191;
        const float* Wp = (p == 0) ? W7 : (p == 1) ? W8 : W9;
        w789[i] = (half_t)Wp[r];
    } else if (idx < 3575 + 24576 + 8192) {
        int i = idx - 28151;
        int p = i >> 12, r = i & 4095;
        wab[i] = (half_t)(p ? W11[r] : W10[r]);
    }
}

// ---------------------------------------------------------------------------
// Kernel 1: q/k/v = gelu(concat(X,STE) @ W.T + b) via f16 MFMA.
// R9 version: 512 thr (8 waves), 64-row tiles, weight LDS ping-pong.
// ---------------------------------------------------------------------------
#define XS 136   // half stride per 128-k row

__device__ __forceinline__ void qkv_stage_w(const half_t* __restrict__ src,
                                            half_t* dst, int tid)
{
    #pragma unroll
    for (int idx = tid; idx < 1024; idx += 512) {
        int c = idx >> 4, g = idx & 15;
        *(uint4*)&dst[c * XS + g * 8] = *(const uint4*)&src[c * 128 + g * 8];
    }
}

__device__ __forceinline__ void qkv_compute(
    const half_t* x16, const half_t* wb, const float* __restrict__ b,
    half_t* __restrict__ outp, float oscale,
    int row0, int rbase, int ch, int l15, int quad)
{
    float4_t acc[2];
    #pragma unroll
    for (int cc = 0; cc < 2; ++cc) {
        float bias = b[(ch * 2 + cc) * 16 + l15];
        acc[cc] = (float4_t){bias, bias, bias, bias};
    }
    #pragma unroll
    for (int kk = 0; kk < 8; ++kk) {
        half4_t a = *(const half4_t*)&x16[(rbase + l15) * XS + kk * 16 + quad * 4];
        #pragma unroll
        for (int cc = 0; cc < 2; ++cc) {
            half4_t bf = *(const half4_t*)
                &wb[((ch * 2 + cc) * 16 + l15) * XS + kk * 16 + quad * 4];
            acc[cc] = __builtin_amdgcn_mfma_f32_16x16x16f16(a, bf, acc[cc], 0, 0, 0);
        }
    }
    #pragma unroll
    for (int cc = 0; cc < 2; ++cc) {
        #pragma unroll
        for (int rr = 0; rr < 4; ++rr) {
            int R = row0 + rbase + quad * 4 + rr;
            if (R < NROWS)
                outp[R * 64 + (ch * 2 + cc) * 16 + l15] =
                    (half_t)(gelu_f(acc[cc][rr]) * oscale);
        }
    }
}

__global__ __launch_bounds__(512) void qkv_kernel(
    const float* __restrict__ X, const float* __restrict__ STE,
    const half_t* __restrict__ w789,
    const float* __restrict__ b7, const float* __restrict__ b8,
    const float* __restrict__ b9,
    half_t* __restrict__ q, half_t* __restrict__ k, half_t* __restrict__ v)
{
    __shared__ __attribute__((aligned(16))) half_t x16[64 * XS];
    __shared__ __attribute__((aligned(16))) half_t wbuf[2][64 * XS];
    const int tid  = threadIdx.x;
    const int row0 = blockIdx.x * 64;

    // stage x = concat(X, STE) -> f16
    #pragma unroll
    for (int idx = tid; idx < 2048; idx += 512) {
        int r = idx >> 5, c4 = idx & 31;
        int R = row0 + r;
        float4 f = {0.f, 0.f, 0.f, 0.f};
        if (R < NROWS)
            f = (c4 < 16) ? *(const float4*)(X + R * 64 + c4 * 4)
                          : *(const float4*)(STE + R * 64 + (c4 - 16) * 4);
        half4_t hv;
        hv[0] = (half_t)f.x; hv[1] = (half_t)f.y;
        hv[2] = (half_t)f.z; hv[3] = (half_t)f.w;
        *(half4_t*)&x16[r * XS + c4 * 4] = hv;
    }
    qkv_stage_w(w789, wbuf[0], tid);          // W7
    __syncthreads();

    const int lane = tid & 63, wv = tid >> 6;
    const int l15 = lane & 15, quad = lane >> 4;
    const int rbase = (wv & 3) * 16, ch = wv >> 2;

    qkv_stage_w(w789 + 8192, wbuf[1], tid);   // W8 (overlaps phase 0)
    qkv_compute(x16, wbuf[0], b7, q, SCL, row0, rbase, ch, l15, quad);
    __syncthreads();

    qkv_stage_w(w789 + 16384, wbuf[0], tid);  // W9 (overlaps phase 1)
    qkv_compute(x16, wbuf[1], b8, k, 1.0f, row0, rbase, ch, l15, quad);
    __syncthreads();

    qkv_compute(x16, wbuf[0], b9, v, 1.0f, row0, rbase, ch, l15, quad);
}

// ---------------------------------------------------------------------------
// Kernel 2: MFMA flash attention v4 — TWO n-tiles per wave, jointly.
// Wave wv processes tile pairs (8i + 2wv, 8i + 2wv + 1), i = 0..2; each
// kf/vf LDS fragment read feeds both tiles (2 independent MFMA chains ->
// intra-wave ILP; LDS fragment traffic halved). Inactive tail tiles are
// predicated (zero qf, guarded store).
// ---------------------------------------------------------------------------
__global__ __launch_bounds__(256) void attn_kernel(
    const half_t* __restrict__ q16g, const half_t* __restrict__ k16g,
    const half_t* __restrict__ v16g, const unsigned int* __restrict__ packedT,
    half_t* __restrict__ ao)
{
    __shared__ __attribute__((aligned(16))) half_t K16[336 * 20]; // [m][d0..15,pad]
    __shared__ __attribute__((aligned(16))) half_t VT16[16 * 344];// [c][m]
    const int tid = threadIdx.x;
    const int h = blockIdx.x, bt = blockIdx.y;
    const long base = (long)(bt * NN) * 64 + h * 8;

    const half4_t z4 = {(half_t)0.f, (half_t)0.f, (half_t)0.f, (half_t)0.f};

    // zero VT16, then ones row c=8 (sum-via-MFMA trick)
    for (int idx = tid; idx < 16 * 344 / 2; idx += 256)
        ((half2_t*)VT16)[idx] = (half2_t)(half_t)0.f;
    __syncthreads();
    for (int i = tid; i < 344; i += 256)
        VT16[8 * 344 + i] = (half_t)1.0f;

    // stage K rows (stride 20, d 8..15 zero)
    for (int r = tid; r < 336; r += 256) {
        half4_t ka = z4, kb = z4;
        if (r < NN) {
            ka = *(const half4_t*)(k16g + base + r * 64);
            kb = *(const half4_t*)(k16g + base + r * 64 + 4);
        }
        *(half4_t*)&K16[r * 20]      = ka;
        *(half4_t*)&K16[r * 20 + 4]  = kb;
        *(half4_t*)&K16[r * 20 + 8]  = z4;
        *(half4_t*)&K16[r * 20 + 12] = z4;
    }

    // stage V transposed via m-pair half2 writes (rows c = 0..7)
    for (int mp = tid; mp < 168; mp += 256) {
        int m0 = 2 * mp, m1 = 2 * mp + 1;
        half4_t v0a = z4, v0b = z4, v1a = z4, v1b = z4;
        if (m0 < NN) {
            v0a = *(const half4_t*)(v16g + base + m0 * 64);
            v0b = *(const half4_t*)(v16g + base + m0 * 64 + 4);
        }
        if (m1 < NN) {
            v1a = *(const half4_t*)(v16g + base + m1 * 64);
            v1b = *(const half4_t*)(v16g + base + m1 * 64 + 4);
        }
        #pragma unroll
        for (int c = 0; c < 4; ++c) {
            half2_t p0; p0[0] = v0a[c]; p0[1] = v1a[c];
            half2_t p1; p1[0] = v0b[c]; p1[1] = v1b[c];
            *(half2_t*)&VT16[c * 344 + 2 * mp]       = p0;
            *(half2_t*)&VT16[(c + 4) * 344 + 2 * mp] = p1;
        }
    }
    __syncthreads();

    const int lane = tid & 63;
    const int wv   = tid >> 6;
    const int l15  = lane & 15;
    const int quad = lane >> 4;
    const int qsh  = quad * 4;

    for (int i = 0; i < 3; ++i) {
        const int tA = 8 * i + 2 * wv;       // 0..22
        const int tB = tA + 1;
        const bool aA = (tA < 21), aB = (tB < 21);
        const int nA = tA * 16 + l15;
        const int nB = tB * 16 + l15;
        const int nqA = (nA < NN) ? nA : (NN - 1);
        const int nqB = (nB < NN) ? nB : (NN - 1);

        half4_t qfA = z4, qfB = z4;
        if (quad < 2 && aA)
            qfA = *(const half4_t*)(q16g + base + (long)nqA * 64 + qsh);
        if (quad < 2 && aB)
            qfB = *(const half4_t*)(q16g + base + (long)nqB * 64 + qsh);

        // pass A: unmasked row max for both tiles (shared kf read)
        float rmA = 0.0f, rmB = 0.0f;
        #pragma unroll
        for (int mt = 0; mt < 21; ++mt) {
            half4_t kf = *(const half4_t*)&K16[(mt * 16 + l15) * 20 + qsh];
            float4_t sA = __builtin_amdgcn_mfma_f32_16x16x16f16(
                kf, qfA, (float4_t){0.f, 0.f, 0.f, 0.f}, 0, 0, 0);
            float4_t sB = __builtin_amdgcn_mfma_f32_16x16x16f16(
                kf, qfB, (float4_t){0.f, 0.f, 0.f, 0.f}, 0, 0, 0);
            rmA = fmaxf(rmA, fmaxf(fmaxf(sA[0], sA[1]), fmaxf(sA[2], sA[3])));
            rmB = fmaxf(rmB, fmaxf(fmaxf(sB[0], sB[1]), fmaxf(sB[2], sB[3])));
        }
        rmA = fmaxf(rmA, __shfl_xor(rmA, 16, 64));
        rmA = fmaxf(rmA, __shfl_xor(rmA, 32, 64));
        rmB = fmaxf(rmB, __shfl_xor(rmB, 16, 64));
        rmB = fmaxf(rmB, __shfl_xor(rmB, 32, 64));

        // mask words for both rows
        unsigned int mbA[11], mbB[11];
        #pragma unroll
        for (int w = 0; w < 11; ++w) {
            mbA[w] = packedT[w * NN + nqA];
            mbB[w] = packedT[w * NN + nqB];
        }

        // pass B: s' = K.Q^T - rm, p = exp2(s'), PV (shared kf/vf reads)
        const float4_t cinitA = {-rmA, -rmA, -rmA, -rmA};
        const float4_t cinitB = {-rmB, -rmB, -rmB, -rmB};
        float4_t accA = {0.f, 0.f, 0.f, 0.f};
        float4_t accB = {0.f, 0.f, 0.f, 0.f};
        #pragma unroll
        for (int mt = 0; mt < 21; ++mt) {
            half4_t kf = *(const half4_t*)&K16[(mt * 16 + l15) * 20 + qsh];
            half4_t vf = *(const half4_t*)&VT16[l15 * 344 + mt * 16 + qsh];
            float4_t sA = __builtin_amdgcn_mfma_f32_16x16x16f16(
                kf, qfA, cinitA, 0, 0, 0);
            float4_t sB = __builtin_amdgcn_mfma_f32_16x16x16f16(
                kf, qfB, cinitB, 0, 0, 0);
            unsigned int shA = mbA[mt >> 1] >> (((mt & 1) << 4) + qsh);
            unsigned int shB = mbB[mt >> 1] >> (((mt & 1) << 4) + qsh);
            half4_t pfA, pfB;
            pfA[0] = (half_t)((shA & 1u) ? __builtin_amdgcn_exp2f(sA[0]) : 0.f);
            pfA[1] = (half_t)((shA & 2u) ? __builtin_amdgcn_exp2f(sA[1]) : 0.f);
            pfA[2] = (half_t)((shA & 4u) ? __builtin_amdgcn_exp2f(sA[2]) : 0.f);
            pfA[3] = (half_t)((shA & 8u) ? __builtin_amdgcn_exp2f(sA[3]) : 0.f);
            pfB[0] = (half_t)((shB & 1u) ? __builtin_amdgcn_exp2f(sB[0]) : 0.f);
            pfB[1] = (half_t)((shB & 2u) ? __builtin_amdgcn_exp2f(sB[1]) : 0.f);
            pfB[2] = (half_t)((shB & 4u) ? __builtin_amdgcn_exp2f(sB[2]) : 0.f);
            pfB[3] = (half_t)((shB & 8u) ? __builtin_amdgcn_exp2f(sB[3]) : 0.f);
            accA = __builtin_amdgcn_mfma_f32_16x16x16f16(vf, pfA, accA, 0, 0, 0);
            accB = __builtin_amdgcn_mfma_f32_16x16x16f16(vf, pfB, accB, 0, 0, 0);
        }

        // sums live in quad=2 lanes (ones row c=8)
        float sumA = __shfl(accA[0], 32 + l15, 64);
        float sumB = __shfl(accB[0], 32 + l15, 64);

        if (quad < 2 && aA && nA < NN) {
            float inv = 1.0f / sumA;
            half4_t o;
            o[0] = (half_t)(accA[0] * inv); o[1] = (half_t)(accA[1] * inv);
            o[2] = (half_t)(accA[2] * inv); o[3] = (half_t)(accA[3] * inv);
            *(half4_t*)(ao + base + (long)nA * 64 + qsh) = o;
        }
        if (quad < 2 && aB && nB < NN) {
            float inv = 1.0f / sumB;
            half4_t o;
            o[0] = (half_t)(accB[0] * inv); o[1] = (half_t)(accB[1] * inv);
            o[2] = (half_t)(accB[2] * inv); o[3] = (half_t)(accB[3] * inv);
            *(half4_t*)(ao + base + (long)nB * 64 + qsh) = o;
        }
    }
}

// ---------------------------------------------------------------------------
// Kernel 3: out = gelu(ao @ W10.T + b10) @ W11.T + b11 via f16 MFMA.
// R9 version: 512 thr, 64-row tiles.
// ---------------------------------------------------------------------------
#define PS 72   // half stride per 64-k row

__global__ __launch_bounds__(512) void proj_kernel(
    const half_t* __restrict__ ao, const half_t* __restrict__ wab,
    const float* __restrict__ b10, const float* __restrict__ b11,
    float* __restrict__ out)
{
    __shared__ __attribute__((aligned(16))) half_t a16[64 * PS];
    __shared__ __attribute__((aligned(16))) half_t wA[64 * PS];
    __shared__ __attribute__((aligned(16))) half_t wB[64 * PS];
    __shared__ __attribute__((aligned(16))) half_t h16[64 * PS];
    const int tid  = threadIdx.x;
    const int row0 = blockIdx.x * 64;

    for (int idx = tid; idx < 512; idx += 512) {
        int r = idx >> 3, c8 = idx & 7;
        int R = row0 + r;
        uint4 u = {0u, 0u, 0u, 0u};
        if (R < NROWS) u = *(const uint4*)(ao + (long)R * 64 + c8 * 8);
        *(uint4*)&a16[r * PS + c8 * 8] = u;
        *(uint4*)&wA[r * PS + c8 * 8] = *(const uint4*)&wab[r * 64 + c8 * 8];
        *(uint4*)&wB[r * PS + c8 * 8] = *(const uint4*)&wab[4096 + r * 64 + c8 * 8];
    }
    __syncthreads();

    const int lane = tid & 63, wv = tid >> 6;
    const int l15 = lane & 15, quad = lane >> 4;
    const int rbase = (wv & 3) * 16, ch = wv >> 2;

    // stage 1: h = gelu(a @ W10.T + b10)
    float4_t acc[2];
    #pragma unroll
    for (int cc = 0; cc < 2; ++cc) {
        float bias = b10[(ch * 2 + cc) * 16 + l15];
        acc[cc] = (float4_t){bias, bias, bias, bias};
    }
    #pragma unroll
    for (int kk = 0; kk < 4; ++kk) {
        half4_t a = *(const half4_t*)&a16[(rbase + l15) * PS + kk * 16 + quad * 4];
        #pragma unroll
        for (int cc = 0; cc < 2; ++cc) {
            half4_t bf = *(const half4_t*)
                &wA[((ch * 2 + cc) * 16 + l15) * PS + kk * 16 + quad * 4];
            acc[cc] = __builtin_amdgcn_mfma_f32_16x16x16f16(a, bf, acc[cc], 0, 0, 0);
        }
    }
    #pragma unroll
    for (int cc = 0; cc < 2; ++cc) {
        #pragma unroll
        for (int rr = 0; rr < 4; ++rr)
            h16[(rbase + quad * 4 + rr) * PS + (ch * 2 + cc) * 16 + l15] =
                (half_t)gelu_f(acc[cc][rr]);
    }
    __syncthreads();

    // stage 2: out = h @ W11.T + b11
    #pragma unroll
    for (int cc = 0; cc < 2; ++cc) {
        float bias = b11[(ch * 2 + cc) * 16 + l15];
        acc[cc] = (float4_t){bias, bias, bias, bias};
    }
    #pragma unroll
    for (int kk = 0; kk < 4; ++kk) {
        half4_t a = *(const half4_t*)&h16[(rbase + l15) * PS + kk * 16 + quad * 4];
        #pragma unroll
        for (int cc = 0; cc < 2; ++cc) {
            half4_t bf = *(const half4_t*)
                &wB[((ch * 2 + cc) * 16 + l15) * PS + kk * 16 + quad * 4];
            acc[cc] = __builtin_amdgcn_mfma_f32_16x16x16f16(a, bf, acc[cc], 0, 0, 0);
        }
    }
    #pragma unroll
    for (int cc = 0; cc < 2; ++cc) {
        #pragma unroll
        for (int rr = 0; rr < 4; ++rr) {
            int R = row0 + rbase + quad * 4 + rr;
            if (R < NROWS)
                out[R * 64 + (ch * 2 + cc) * 16 + l15] = acc[cc][rr];
        }
    }
}

extern "C" void kernel_launch(void* const* d_in, const int* in_sizes, int n_in,
                              void* d_out, int out_size, void* d_ws, size_t ws_size,
                              hipStream_t stream) {
    const float* X   = (const float*)d_in[0];
    const float* STE = (const float*)d_in[1];
    const int*   adj = (const int*)d_in[2];
    const float* W7  = (const float*)d_in[3];
    const float* b7  = (const float*)d_in[4];
    const float* W8  = (const float*)d_in[5];
    const float* b8  = (const float*)d_in[6];
    const float* W9  = (const float*)d_in[7];
    const float* b9  = (const float*)d_in[8];
    const float* W10 = (const float*)d_in[9];
    const float* b10 = (const float*)d_in[10];
    const float* W11 = (const float*)d_in[11];
    const float* b11 = (const float*)d_in[12];

    char* wsb = (char*)d_ws;
    const long S = (long)NROWS * 64;           // 1,996,800 elements
    half_t* qb = (half_t*)wsb;
    half_t* kb = qb + S;
    half_t* vb = qb + 2 * S;
    half_t* ab = qb + 3 * S;
    unsigned int* pk = (unsigned int*)(wsb + 4 * S * sizeof(half_t));
    half_t* w789 = (half_t*)(wsb + 4 * S * sizeof(half_t) + 16384);
    half_t* wab  = w789 + 24576;

    prep_kernel<<<142, 256, 0, stream>>>(adj, W7, W8, W9, W10, W11,
                                         pk, w789, wab);
    qkv_kernel<<<dim3((NROWS + 63) / 64), 512, 0, stream>>>(
        X, STE, w789, b7, b8, b9, qb, kb, vb);
    attn_kernel<<<dim3(8, BT), 256, 0, stream>>>(qb, kb, vb, pk, ab);
    proj_kernel<<<dim3((NROWS + 63) / 64), 512, 0, stream>>>(
        ab, wab, b10, b11, (float*)d_out);
}